// Round 13
// baseline (136.946 us; speedup 1.0000x reference)
//
#include <hip/hip_runtime.h>
#include <math.h>

#define EPS 1e-7f

constexpr int B = 16, L = 1024, D = 256, P = 20;
constexpr int LD = L * D;     // 262144
constexpr int DD = D * D;     // 65536
constexpr size_t KCS = (size_t)B * DD;   // Gp16 kc-stride (halfs)

typedef __attribute__((ext_vector_type(8))) _Float16 f16x8;
typedef __attribute__((ext_vector_type(4))) float f32x4;

// ---------------------------------------------------------------------------
// ws layout (float slots).  NO atomics, NO memsets.
//   tp    @0         131072    fp32 [32][B][D]  t partials
//   invU  @131072    16384     fp32 [B*L]  (only sign consumed downstream)
//   s1f   @147456    2097152   fp16 [B*L][D]
//   CT    @2244608   2097152   fp16 [B][D][L]  (s2*sqrt(invn2), transposed)
//   Gp16  @4341760   2097152   fp16 [4][B][D][D]  gram K-split partials
//   mavh  @6438912   2097152   fp16 [B*L][D]  (unscaled u; out scale-invariant)
// total 8536064 floats = 34.1 MB
// ---------------------------------------------------------------------------

__device__ inline unsigned short f2h(float x) {
    _Float16 h = (_Float16)x;
    union { _Float16 h; unsigned short u; } c; c.h = h; return c.u;
}
__device__ inline float h2f(unsigned short u) {
    union { unsigned short u; _Float16 h; } c; c.u = u; return (float)c.h;
}

// K1: one pass over s2.  Block = 32 full rows (b, m0..m0+31).  Computes
// invn2 locally, emits tp partials and transposed fp16 CT.  Grid 512.
__global__ __launch_bounds__(256) void k_prep2(const float* __restrict__ s2,
                                               float* __restrict__ tp,
                                               unsigned short* __restrict__ CT) {
    __shared__ float tile[32][257];
    __shared__ float wiv[32];   // invn2 = 1/norm
    __shared__ float wsq[32];   // sqrt(invn2)
    int tid = threadIdx.x;
    int b   = blockIdx.x >> 5, mt = blockIdx.x & 31;
    int m0  = mt * 32;
    {
        int r = tid >> 3, c0 = (tid & 7) * 32;
        const float* gp = s2 + (size_t)b * LD + (size_t)(m0 + r) * D + c0;
        float4 v[8];
#pragma unroll
        for (int q = 0; q < 8; ++q) v[q] = ((const float4*)gp)[q];
#pragma unroll
        for (int q = 0; q < 8; ++q) *(float4*)&tile[r][c0 + q * 4] = v[q];
    }
    __syncthreads();
    {
        int r = tid >> 3, seg = tid & 7;
        float s = 0.f;
#pragma unroll
        for (int k = 0; k < 32; ++k) { float v = tile[r][seg * 32 + k]; s += v * v; }
#pragma unroll
        for (int o = 4; o; o >>= 1) s += __shfl_down(s, o, 8);
        if (seg == 0) {
            float iv = 1.0f / sqrtf(fmaxf(s, EPS));
            wiv[r] = iv;
            wsq[r] = sqrtf(iv);
        }
    }
    __syncthreads();
    {
        int dc = tid;                          // d-column 0..255
        float tpart = 0.f;
        union { unsigned short us[32]; uint4 q[4]; } ph;
#pragma unroll
        for (int m = 0; m < 32; ++m) {
            float v = tile[m][dc];
            tpart += v * wiv[m];
            ph.us[m] = f2h(v * wsq[m]);
        }
        tp[(size_t)(mt * B + b) * D + dc] = tpart;
        size_t o = (size_t)b * LD + (size_t)dc * L + m0;
        *(uint4*)(CT + o)      = ph.q[0]; *(uint4*)(CT + o + 8)  = ph.q[1];
        *(uint4*)(CT + o + 16) = ph.q[2]; *(uint4*)(CT + o + 24) = ph.q[3];
    }
}

// K2: one pass over s1.  Reduces t-partials, computes invU (fp32, exact sign
// path), writes fp16 s1f.  One wave per row; grid 4096.
__global__ __launch_bounds__(256) void k_u(const float* __restrict__ s1,
                                           const float* __restrict__ tp,
                                           float* __restrict__ invU,
                                           unsigned short* __restrict__ s1f) {
    __shared__ float ts[D];
    int tid = threadIdx.x;
    {
        int b0 = (blockIdx.x * 4) >> 10;      // all 4 rows share b
        float acc = 0.f;
#pragma unroll
        for (int mc = 0; mc < 32; ++mc)
            acc += tp[(size_t)(mc * B + b0) * D + tid];
        ts[tid] = acc;
    }
    __syncthreads();

    int w = tid >> 6, lane = tid & 63;
    int row = blockIdx.x * 4 + w;             // 0..16383
    int dg = lane & 15;

    float4 sv[4];
    float up = 0.f, sq = 0.f;
#pragma unroll
    for (int j = 0; j < 4; ++j) {
        sv[j] = *(const float4*)(s1 + (size_t)row * D + dg * 4 + j * 64);
        float4 tv = *(const float4*)(ts + dg * 4 + j * 64);
        up += sv[j].x * tv.x + sv[j].y * tv.y + sv[j].z * tv.z + sv[j].w * tv.w;
        sq += sv[j].x * sv[j].x + sv[j].y * sv[j].y + sv[j].z * sv[j].z + sv[j].w * sv[j].w;
    }
#pragma unroll
    for (int o = 8; o; o >>= 1) {
        up += __shfl_down(up, o, 16);
        sq += __shfl_down(sq, o, 16);
    }
    if (lane == 0) {
        float n1v = sqrtf(fmaxf(sq, EPS));
        invU[row] = 1.0f / (up + EPS * n1v);
    }
#pragma unroll
    for (int j = 0; j < 4; ++j) {
        ushort4 h4;
        h4.x = f2h(sv[j].x); h4.y = f2h(sv[j].y);
        h4.z = f2h(sv[j].z); h4.w = f2h(sv[j].w);
        *(ushort4*)(s1f + (size_t)row * D + dg * 4 + j * 64) = h4;
    }
}

// K3: Gram via fp16 MFMA, single pass.  Writes fp16 partials Gp16[kc].
// Block: 128(i) x 64(j) tile, 4 waves 2x2 (64x32 each, 4x2 MFMA 16x16x32).
// Grid: 16 b x (2 ti x 4 tj x 4 kc) = 512 -> 2 blocks/CU.
__global__ __launch_bounds__(256) void k_gram_mfma(const unsigned short* __restrict__ CT,
                                                   unsigned short* __restrict__ Gp16) {
    __shared__ short As[128 * 72];
    __shared__ short Bs[64 * 72];
    int tid  = threadIdx.x;
    int b    = blockIdx.x >> 5;
    int rem  = blockIdx.x & 31;
    int ti   = rem >> 4;               // 0..1
    int tj   = (rem >> 2) & 3;         // 0..3
    int kc   = rem & 3;                // 0..3
    int wave = tid >> 6, lane = tid & 63;
    int wr   = (wave >> 1) * 64, wcc = (wave & 1) * 32;
    int lr   = lane & 15, lq = lane >> 4;
    int arow = tid >> 1, ahalf = (tid & 1) * 32;   // A: 128 rows, 2 thr/row
    int brow = tid >> 2, bq = (tid & 3) * 16;      // B: 64 rows, 4 thr/row

    f32x4 acc[4][2];
#pragma unroll
    for (int i = 0; i < 4; ++i)
#pragma unroll
        for (int j = 0; j < 2; ++j) acc[i][j] = (f32x4){0.f, 0.f, 0.f, 0.f};

#pragma unroll 1
    for (int kb = 0; kb < 4; ++kb) {
        int koff = kc * 256 + kb * 64;
        __syncthreads();
        {
            const unsigned short* ga = CT + (size_t)b * LD + (size_t)(ti * 128 + arow) * L + koff + ahalf;
            uint4 a0 = ((const uint4*)ga)[0], a1 = ((const uint4*)ga)[1];
            uint4 a2 = ((const uint4*)ga)[2], a3 = ((const uint4*)ga)[3];
            const unsigned short* gb = CT + (size_t)b * LD + (size_t)(tj * 64 + brow) * L + koff + bq;
            uint4 b0 = ((const uint4*)gb)[0], b1 = ((const uint4*)gb)[1];
            short* la = &As[arow * 72 + ahalf];
            ((uint4*)la)[0] = a0; ((uint4*)la)[1] = a1;
            ((uint4*)la)[2] = a2; ((uint4*)la)[3] = a3;
            short* lb = &Bs[brow * 72 + bq];
            ((uint4*)lb)[0] = b0; ((uint4*)lb)[1] = b1;
        }
        __syncthreads();
#pragma unroll
        for (int ks = 0; ks < 2; ++ks) {
            f16x8 af[4], bfr[2];
#pragma unroll
            for (int i = 0; i < 4; ++i)
                af[i] = *(const f16x8*)&As[(wr + i * 16 + lr) * 72 + ks * 32 + lq * 8];
#pragma unroll
            for (int j = 0; j < 2; ++j)
                bfr[j] = *(const f16x8*)&Bs[(wcc + j * 16 + lr) * 72 + ks * 32 + lq * 8];
#pragma unroll
            for (int i = 0; i < 4; ++i)
#pragma unroll
                for (int j = 0; j < 2; ++j)
                    acc[i][j] = __builtin_amdgcn_mfma_f32_16x16x32_f16(af[i], bfr[j], acc[i][j], 0, 0, 0);
        }
    }
    unsigned short* gout = Gp16 + (size_t)(kc * B + b) * DD;
#pragma unroll
    for (int i = 0; i < 4; ++i)
#pragma unroll
        for (int r = 0; r < 4; ++r) {
            int row = ti * 128 + wr + i * 16 + lq * 4 + r;
#pragma unroll
            for (int j = 0; j < 2; ++j)
                gout[(size_t)row * D + tj * 64 + wcc + j * 16 + lr] = f2h(acc[i][j][r]);
        }
}

// K4: mavh = fp16(s1 @ G), with the 4 fp16 Gram partials summed INLINE in
// the B-staging (packed-fp16 adds) — reduceG kernel deleted.
// Block = 64 l x 128 n, 4 waves each 64l x 32n (4x2 MFMA).  Grid 512.
__global__ __launch_bounds__(256) void k_mav_mfma(const unsigned short* __restrict__ s1f,
                                                  const unsigned short* __restrict__ Gp16,
                                                  unsigned short* __restrict__ mavh) {
    __shared__ short As[64 * 72];
    __shared__ short Bs[128 * 72];
    int tid  = threadIdx.x;
    int b    = blockIdx.x >> 5;
    int rem  = blockIdx.x & 31;
    int lt   = rem >> 1, nt = rem & 1;
    int l0   = lt * 64, n0 = nt * 128;
    int wave = tid >> 6, lane = tid & 63;
    int wn   = wave * 32;
    int lr   = lane & 15, lq = lane >> 4;
    int arow = tid >> 2, aq = (tid & 3) * 16;      // A: 64 rows x 64 shorts
    int brow = tid >> 1, bhalf = (tid & 1) * 32;   // B: 128 rows x 64 shorts

    f32x4 acc[4][2];
#pragma unroll
    for (int i = 0; i < 4; ++i)
#pragma unroll
        for (int j = 0; j < 2; ++j) acc[i][j] = (f32x4){0.f, 0.f, 0.f, 0.f};

#pragma unroll 1
    for (int kb = 0; kb < 4; ++kb) {
        int koff = kb * 64;
        __syncthreads();
        {
            const unsigned short* ga = s1f + (size_t)(b * L + l0 + arow) * D + koff + aq;
            uint4 a0 = ((const uint4*)ga)[0], a1 = ((const uint4*)ga)[1];
            short* la = &As[arow * 72 + aq];
            ((uint4*)la)[0] = a0; ((uint4*)la)[1] = a1;
            // B: sum the 4 fp16 gram partials inline (v_pk_add_f16)
            const unsigned short* gb = Gp16 + (size_t)b * DD + (size_t)(n0 + brow) * D + koff + bhalf;
            short* lb = &Bs[brow * 72 + bhalf];
            union PH { uint4 q; f16x8 h; };
#pragma unroll
            for (int c = 0; c < 4; ++c) {
                PH p0, p1, p2, p3, s;
                p0.q = *(const uint4*)(gb + c * 8);
                p1.q = *(const uint4*)(gb + KCS + c * 8);
                p2.q = *(const uint4*)(gb + 2 * KCS + c * 8);
                p3.q = *(const uint4*)(gb + 3 * KCS + c * 8);
                s.h = (p0.h + p1.h) + (p2.h + p3.h);
                ((uint4*)lb)[c] = s.q;
            }
        }
        __syncthreads();
#pragma unroll
        for (int ks = 0; ks < 2; ++ks) {
            f16x8 af[4], bfr[2];
#pragma unroll
            for (int i = 0; i < 4; ++i)
                af[i] = *(const f16x8*)&As[(i * 16 + lr) * 72 + ks * 32 + lq * 8];
#pragma unroll
            for (int j = 0; j < 2; ++j)
                bfr[j] = *(const f16x8*)&Bs[(wn + j * 16 + lr) * 72 + ks * 32 + lq * 8];
#pragma unroll
            for (int i = 0; i < 4; ++i)
#pragma unroll
                for (int j = 0; j < 2; ++j)
                    acc[i][j] = __builtin_amdgcn_mfma_f32_16x16x32_f16(af[i], bfr[j], acc[i][j], 0, 0, 0);
        }
    }
#pragma unroll
    for (int i = 0; i < 4; ++i)
#pragma unroll
        for (int r = 0; r < 4; ++r) {
            int l = l0 + i * 16 + lq * 4 + r;
#pragma unroll
            for (int j = 0; j < 2; ++j)
                mavh[(size_t)(b * L + l) * D + n0 + wn + j * 16 + lr] = f2h(acc[i][j][r]);
        }
}

// K5: out[row,p] = sign(invU) * na * rsqrt(nb) * rsqrt(nc) over fp16 s1f/mavh.
__global__ __launch_bounds__(256) void k_out(const unsigned short* __restrict__ s1f,
                                             const unsigned short* __restrict__ mavh,
                                             const float* __restrict__ invU,
                                             const float* __restrict__ kern,
                                             float* __restrict__ out) {
    __shared__ float k2s[P * D];
    int tid = threadIdx.x;
#pragma unroll
    for (int p = 0; p < P; ++p) {
        float v = kern[p * D + tid];
        k2s[p * D + tid] = v * v;
    }
    __syncthreads();

    int w = tid >> 6, lane = tid & 63;
    int row = blockIdx.x * 4 + w;
    int dg = lane & 15, ps = lane >> 4;

    float4 sm[4], ss[4], mm[4];
#pragma unroll
    for (int j = 0; j < 4; ++j) {
        ushort4 h4 = *(const ushort4*)(s1f + (size_t)row * D + dg * 4 + j * 64);
        ushort4 m4 = *(const ushort4*)(mavh + (size_t)row * D + dg * 4 + j * 64);
        float4 sv, mv;
        sv.x = h2f(h4.x); sv.y = h2f(h4.y); sv.z = h2f(h4.z); sv.w = h2f(h4.w);
        mv.x = h2f(m4.x); mv.y = h2f(m4.y); mv.z = h2f(m4.z); mv.w = h2f(m4.w);
        sm[j].x = sv.x * mv.x; sm[j].y = sv.y * mv.y; sm[j].z = sv.z * mv.z; sm[j].w = sv.w * mv.w;
        ss[j].x = sv.x * sv.x; ss[j].y = sv.y * sv.y; ss[j].z = sv.z * sv.z; ss[j].w = sv.w * sv.w;
        mm[j].x = mv.x * mv.x; mm[j].y = mv.y * mv.y; mm[j].z = mv.z * mv.z; mm[j].w = mv.w * mv.w;
    }
    float sgn = (invU[row] < 0.f) ? -1.f : 1.f;
#pragma unroll
    for (int tI = 0; tI < 5; ++tI) {
        int p = ps + tI * 4;
        float na = 0.f, nb = 0.f, nc = 0.f;
#pragma unroll
        for (int j = 0; j < 4; ++j) {
            float4 kv = *(const float4*)&k2s[p * D + j * 64 + dg * 4];
            na += sm[j].x * kv.x + sm[j].y * kv.y + sm[j].z * kv.z + sm[j].w * kv.w;
            nb += ss[j].x * kv.x + ss[j].y * kv.y + ss[j].z * kv.z + ss[j].w * kv.w;
            nc += mm[j].x * kv.x + mm[j].y * kv.y + mm[j].z * kv.z + mm[j].w * kv.w;
        }
#pragma unroll
        for (int o = 8; o; o >>= 1) {
            na += __shfl_down(na, o, 16);
            nb += __shfl_down(nb, o, 16);
            nc += __shfl_down(nc, o, 16);
        }
        if (dg == 0) {
            out[(size_t)row * P + p] = sgn * na * rsqrtf(fmaxf(nb, EPS)) *
                                       rsqrtf(fmaxf(nc, EPS));
        }
    }
}

extern "C" void kernel_launch(void* const* d_in, const int* in_sizes, int n_in,
                              void* d_out, int out_size, void* d_ws, size_t ws_size,
                              hipStream_t stream) {
    const float* s1   = (const float*)d_in[0];
    const float* s2   = (const float*)d_in[1];
    const float* kern = (const float*)d_in[2];
    float* out = (float*)d_out;
    float* ws  = (float*)d_ws;

    float* tp   = ws;
    float* invU = ws + 131072;
    unsigned short* s1f  = (unsigned short*)(ws + 147456);
    unsigned short* CT   = (unsigned short*)(ws + 2244608);
    unsigned short* Gp16 = (unsigned short*)(ws + 4341760);
    unsigned short* mavh = (unsigned short*)(ws + 6438912);

    k_prep2<<<512, 256, 0, stream>>>(s2, tp, CT);
    k_u<<<4096, 256, 0, stream>>>(s1, tp, invU, s1f);
    k_gram_mfma<<<512, 256, 0, stream>>>(CT, Gp16);
    k_mav_mfma<<<512, 256, 0, stream>>>(s1f, Gp16, mavh);
    k_out<<<4096, 256, 0, stream>>>(s1f, mavh, invU, kern, out);
}

// Round 14
// 133.189 us; speedup vs baseline: 1.0282x; 1.0282x over previous
//
#include <hip/hip_runtime.h>
#include <math.h>

#define EPS 1e-7f

constexpr int B = 16, L = 1024, D = 256, P = 20;
constexpr int LD = L * D;     // 262144
constexpr int DD = D * D;     // 65536

typedef __attribute__((ext_vector_type(8))) _Float16 f16x8;
typedef __attribute__((ext_vector_type(4))) float f32x4;

// ---------------------------------------------------------------------------
// ws layout (float slots).  NO atomics, NO memsets.
//   tp    @0         131072    fp32 [32][B][D]  t partials
//   invU  @131072    16384     fp32 [B*L]  (only sign consumed downstream)
//   s1f   @147456    2097152   fp16 [B*L][D]
//   CT    @2244608   2097152   fp16 [B][D][L]  (s2*sqrt(invn2), transposed)
//   Gf    @4341760   524288    fp16 [B][D][D]
//   Gp    @4866048   4194304   fp32 [4][B][D][D]  gram K-split partials
// total 9060352 floats = 36.2 MB
// ---------------------------------------------------------------------------

__device__ inline unsigned short f2h(float x) {
    _Float16 h = (_Float16)x;
    union { _Float16 h; unsigned short u; } c; c.h = h; return c.u;
}
__device__ inline float h2f(unsigned short u) {
    union { unsigned short u; _Float16 h; } c; c.u = u; return (float)c.h;
}

// K1: one pass over s2.  Block = 32 full rows (b, m0..m0+31).  Computes
// invn2 locally, emits tp partials and transposed fp16 CT.  Grid 512.
__global__ __launch_bounds__(256) void k_prep2(const float* __restrict__ s2,
                                               float* __restrict__ tp,
                                               unsigned short* __restrict__ CT) {
    __shared__ float tile[32][257];
    __shared__ float wiv[32];   // invn2 = 1/norm
    __shared__ float wsq[32];   // sqrt(invn2)
    int tid = threadIdx.x;
    int b   = blockIdx.x >> 5, mt = blockIdx.x & 31;
    int m0  = mt * 32;
    {
        int r = tid >> 3, c0 = (tid & 7) * 32;
        const float* gp = s2 + (size_t)b * LD + (size_t)(m0 + r) * D + c0;
        float4 v[8];
#pragma unroll
        for (int q = 0; q < 8; ++q) v[q] = ((const float4*)gp)[q];
#pragma unroll
        for (int q = 0; q < 8; ++q) *(float4*)&tile[r][c0 + q * 4] = v[q];
    }
    __syncthreads();
    {
        int r = tid >> 3, seg = tid & 7;
        float s = 0.f;
#pragma unroll
        for (int k = 0; k < 32; ++k) { float v = tile[r][seg * 32 + k]; s += v * v; }
#pragma unroll
        for (int o = 4; o; o >>= 1) s += __shfl_down(s, o, 8);
        if (seg == 0) {
            float iv = 1.0f / sqrtf(fmaxf(s, EPS));
            wiv[r] = iv;
            wsq[r] = sqrtf(iv);
        }
    }
    __syncthreads();
    {
        int dc = tid;                          // d-column 0..255
        float tpart = 0.f;
        union { unsigned short us[32]; uint4 q[4]; } ph;
#pragma unroll
        for (int m = 0; m < 32; ++m) {
            float v = tile[m][dc];
            tpart += v * wiv[m];
            ph.us[m] = f2h(v * wsq[m]);
        }
        tp[(size_t)(mt * B + b) * D + dc] = tpart;
        size_t o = (size_t)b * LD + (size_t)dc * L + m0;
        *(uint4*)(CT + o)      = ph.q[0]; *(uint4*)(CT + o + 8)  = ph.q[1];
        *(uint4*)(CT + o + 16) = ph.q[2]; *(uint4*)(CT + o + 24) = ph.q[3];
    }
}

// K2: one pass over s1.  Reduces t-partials, computes invU (fp32, exact sign
// path), writes fp16 s1f.  One wave per row; grid 4096.
__global__ __launch_bounds__(256) void k_u(const float* __restrict__ s1,
                                           const float* __restrict__ tp,
                                           float* __restrict__ invU,
                                           unsigned short* __restrict__ s1f) {
    __shared__ float ts[D];
    int tid = threadIdx.x;
    {
        int b0 = (blockIdx.x * 4) >> 10;      // all 4 rows share b
        float acc = 0.f;
#pragma unroll
        for (int mc = 0; mc < 32; ++mc)
            acc += tp[(size_t)(mc * B + b0) * D + tid];
        ts[tid] = acc;
    }
    __syncthreads();

    int w = tid >> 6, lane = tid & 63;
    int row = blockIdx.x * 4 + w;             // 0..16383
    int dg = lane & 15;

    float4 sv[4];
    float up = 0.f, sq = 0.f;
#pragma unroll
    for (int j = 0; j < 4; ++j) {
        sv[j] = *(const float4*)(s1 + (size_t)row * D + dg * 4 + j * 64);
        float4 tv = *(const float4*)(ts + dg * 4 + j * 64);
        up += sv[j].x * tv.x + sv[j].y * tv.y + sv[j].z * tv.z + sv[j].w * tv.w;
        sq += sv[j].x * sv[j].x + sv[j].y * sv[j].y + sv[j].z * sv[j].z + sv[j].w * sv[j].w;
    }
#pragma unroll
    for (int o = 8; o; o >>= 1) {
        up += __shfl_down(up, o, 16);
        sq += __shfl_down(sq, o, 16);
    }
    if (lane == 0) {
        float n1v = sqrtf(fmaxf(sq, EPS));
        invU[row] = 1.0f / (up + EPS * n1v);
    }
#pragma unroll
    for (int j = 0; j < 4; ++j) {
        ushort4 h4;
        h4.x = f2h(sv[j].x); h4.y = f2h(sv[j].y);
        h4.z = f2h(sv[j].z); h4.w = f2h(sv[j].w);
        *(ushort4*)(s1f + (size_t)row * D + dg * 4 + j * 64) = h4;
    }
}

// K3: Gram via fp16 MFMA, single pass.  G = C'C, K-split x4 (256 m each).
// Block: 128(i) x 64(j) tile, 4 waves 2x2 (64x32 each, 4x2 MFMA 16x16x32).
// Grid: 16 b x (2 ti x 4 tj x 4 kc) = 512 -> 2 blocks/CU.
__global__ __launch_bounds__(256) void k_gram_mfma(const unsigned short* __restrict__ CT,
                                                   float* __restrict__ Gp) {
    __shared__ short As[128 * 72];
    __shared__ short Bs[64 * 72];
    int tid  = threadIdx.x;
    int b    = blockIdx.x >> 5;
    int rem  = blockIdx.x & 31;
    int ti   = rem >> 4;               // 0..1
    int tj   = (rem >> 2) & 3;         // 0..3
    int kc   = rem & 3;                // 0..3
    int wave = tid >> 6, lane = tid & 63;
    int wr   = (wave >> 1) * 64, wcc = (wave & 1) * 32;
    int lr   = lane & 15, lq = lane >> 4;
    int arow = tid >> 1, ahalf = (tid & 1) * 32;   // A: 128 rows, 2 thr/row
    int brow = tid >> 2, bq = (tid & 3) * 16;      // B: 64 rows, 4 thr/row

    f32x4 acc[4][2];
#pragma unroll
    for (int i = 0; i < 4; ++i)
#pragma unroll
        for (int j = 0; j < 2; ++j) acc[i][j] = (f32x4){0.f, 0.f, 0.f, 0.f};

#pragma unroll 1
    for (int kb = 0; kb < 4; ++kb) {
        int koff = kc * 256 + kb * 64;
        __syncthreads();
        {
            const unsigned short* ga = CT + (size_t)b * LD + (size_t)(ti * 128 + arow) * L + koff + ahalf;
            uint4 a0 = ((const uint4*)ga)[0], a1 = ((const uint4*)ga)[1];
            uint4 a2 = ((const uint4*)ga)[2], a3 = ((const uint4*)ga)[3];
            const unsigned short* gb = CT + (size_t)b * LD + (size_t)(tj * 64 + brow) * L + koff + bq;
            uint4 b0 = ((const uint4*)gb)[0], b1 = ((const uint4*)gb)[1];
            short* la = &As[arow * 72 + ahalf];
            ((uint4*)la)[0] = a0; ((uint4*)la)[1] = a1;
            ((uint4*)la)[2] = a2; ((uint4*)la)[3] = a3;
            short* lb = &Bs[brow * 72 + bq];
            ((uint4*)lb)[0] = b0; ((uint4*)lb)[1] = b1;
        }
        __syncthreads();
#pragma unroll
        for (int ks = 0; ks < 2; ++ks) {
            f16x8 af[4], bfr[2];
#pragma unroll
            for (int i = 0; i < 4; ++i)
                af[i] = *(const f16x8*)&As[(wr + i * 16 + lr) * 72 + ks * 32 + lq * 8];
#pragma unroll
            for (int j = 0; j < 2; ++j)
                bfr[j] = *(const f16x8*)&Bs[(wcc + j * 16 + lr) * 72 + ks * 32 + lq * 8];
#pragma unroll
            for (int i = 0; i < 4; ++i)
#pragma unroll
                for (int j = 0; j < 2; ++j)
                    acc[i][j] = __builtin_amdgcn_mfma_f32_16x16x32_f16(af[i], bfr[j], acc[i][j], 0, 0, 0);
        }
    }
    float* gout = Gp + ((size_t)(kc * B + b)) * DD;
#pragma unroll
    for (int i = 0; i < 4; ++i)
#pragma unroll
        for (int r = 0; r < 4; ++r) {
            int row = ti * 128 + wr + i * 16 + lq * 4 + r;
#pragma unroll
            for (int j = 0; j < 2; ++j)
                gout[(size_t)row * D + tj * 64 + wcc + j * 16 + lr] = acc[i][j][r];
        }
}

// K4: reduce 4 gram partials; emit fp16 Gf.  (Separate clean-BW kernel —
// R12 showed inline strided reduce in mav staging costs ~2x more.)
__global__ __launch_bounds__(256) void k_reduceG(const float* __restrict__ Gp,
                                                 unsigned short* __restrict__ Gf) {
    size_t i = ((size_t)blockIdx.x * 256 + threadIdx.x) * 4;
    float4 s = *(const float4*)(Gp + i);
#pragma unroll
    for (int kc = 1; kc < 4; ++kc) {
        float4 a = *(const float4*)(Gp + (size_t)kc * B * DD + i);
        s.x += a.x; s.y += a.y; s.z += a.z; s.w += a.w;
    }
    ushort4 h4;
    h4.x = f2h(s.x); h4.y = f2h(s.y); h4.z = f2h(s.z); h4.w = f2h(s.w);
    *(ushort4*)(Gf + i) = h4;
}

// K5 (fused mav+out): block = 32 l x 256 n (full D), grid 16 b x 32 lt = 512
// -> 2 blocks/CU.  4 waves each 32l x 64n (2x4 MFMA 16x16x32).  After the
// K-loop the block holds complete mav rows (unscaled u; out is
// scale-invariant in mav, sign(invU) applied at the end): u-tile -> LDS fp16,
// then k_out-style per-row dot products.  mavh HBM round-trip deleted.
union MoSh {
    struct { short As[32 * 72]; short Bs[256 * 72]; } g;     // 41.5 KB
    struct { unsigned short mavs[32][264]; float k2s[P * D]; } e;  // 37.4 KB
};
__global__ __launch_bounds__(256, 2) void k_mavout(const unsigned short* __restrict__ s1f,
                                                   const unsigned short* __restrict__ Gf,
                                                   const float* __restrict__ invU,
                                                   const float* __restrict__ kern,
                                                   float* __restrict__ out) {
    __shared__ MoSh sh;
    int tid  = threadIdx.x;
    int b    = blockIdx.x >> 5;
    int lt   = blockIdx.x & 31;
    int l0   = lt * 32;
    int wave = tid >> 6, lane = tid & 63;
    int wn   = wave * 64;
    int lr   = lane & 15, lq = lane >> 4;
    int arow = tid >> 3, aq = (tid & 7) * 8;       // A: 32 rows x 64 halfs
    int brow = tid >> 1, bhalf = (tid & 1) * 32;   // B: rows brow, brow+128

    f32x4 acc[2][4];
#pragma unroll
    for (int i = 0; i < 2; ++i)
#pragma unroll
        for (int j = 0; j < 4; ++j) acc[i][j] = (f32x4){0.f, 0.f, 0.f, 0.f};

#pragma unroll 1
    for (int kb = 0; kb < 4; ++kb) {
        int koff = kb * 64;
        __syncthreads();
        {
            const unsigned short* ga = s1f + (size_t)(b * L + l0 + arow) * D + koff + aq;
            uint4 a0 = *(const uint4*)ga;
            *(uint4*)&sh.g.As[arow * 72 + aq] = a0;
            const unsigned short* gb0 = Gf + (size_t)b * DD + (size_t)brow * D + koff + bhalf;
            const unsigned short* gb1 = gb0 + (size_t)128 * D;
            uint4 q0 = ((const uint4*)gb0)[0], q1 = ((const uint4*)gb0)[1];
            uint4 q2 = ((const uint4*)gb0)[2], q3 = ((const uint4*)gb0)[3];
            uint4 r0 = ((const uint4*)gb1)[0], r1 = ((const uint4*)gb1)[1];
            uint4 r2 = ((const uint4*)gb1)[2], r3 = ((const uint4*)gb1)[3];
            short* lb0 = &sh.g.Bs[brow * 72 + bhalf];
            short* lb1 = &sh.g.Bs[(brow + 128) * 72 + bhalf];
            ((uint4*)lb0)[0] = q0; ((uint4*)lb0)[1] = q1;
            ((uint4*)lb0)[2] = q2; ((uint4*)lb0)[3] = q3;
            ((uint4*)lb1)[0] = r0; ((uint4*)lb1)[1] = r1;
            ((uint4*)lb1)[2] = r2; ((uint4*)lb1)[3] = r3;
        }
        __syncthreads();
#pragma unroll
        for (int ks = 0; ks < 2; ++ks) {
            f16x8 af[2], bfr[4];
#pragma unroll
            for (int i = 0; i < 2; ++i)
                af[i] = *(const f16x8*)&sh.g.As[(i * 16 + lr) * 72 + ks * 32 + lq * 8];
#pragma unroll
            for (int j = 0; j < 4; ++j)
                bfr[j] = *(const f16x8*)&sh.g.Bs[(wn + j * 16 + lr) * 72 + ks * 32 + lq * 8];
#pragma unroll
            for (int i = 0; i < 2; ++i)
#pragma unroll
                for (int j = 0; j < 4; ++j)
                    acc[i][j] = __builtin_amdgcn_mfma_f32_16x16x32_f16(af[i], bfr[j], acc[i][j], 0, 0, 0);
        }
    }

    // ---- epilogue: u-tile -> LDS (fp16, unscaled), then per-row dots ----
    __syncthreads();   // all MFMA LDS reads done; repurpose union
#pragma unroll
    for (int i = 0; i < 2; ++i)
#pragma unroll
        for (int r = 0; r < 4; ++r) {
            int row = i * 16 + lq * 4 + r;
#pragma unroll
            for (int j = 0; j < 4; ++j)
                sh.e.mavs[row][wn + j * 16 + lr] = f2h(acc[i][j][r]);
        }
#pragma unroll
    for (int p = 0; p < P; ++p) {
        float v = kern[p * D + tid];
        sh.e.k2s[p * D + tid] = v * v;
    }
    __syncthreads();

    int dg = lane & 15, ps = lane >> 4;
#pragma unroll 1
    for (int rr = 0; rr < 8; ++rr) {
        int mrow = wave * 8 + rr;
        int gl   = b * L + l0 + mrow;
        float4 sm[4], ss[4], mm[4];
#pragma unroll
        for (int j = 0; j < 4; ++j) {
            ushort4 h4 = *(const ushort4*)(s1f + (size_t)gl * D + dg * 4 + j * 64);
            ushort4 m4 = *(const ushort4*)&sh.e.mavs[mrow][dg * 4 + j * 64];
            float4 sv, mv;
            sv.x = h2f(h4.x); sv.y = h2f(h4.y); sv.z = h2f(h4.z); sv.w = h2f(h4.w);
            mv.x = h2f(m4.x); mv.y = h2f(m4.y); mv.z = h2f(m4.z); mv.w = h2f(m4.w);
            sm[j].x = sv.x * mv.x; sm[j].y = sv.y * mv.y; sm[j].z = sv.z * mv.z; sm[j].w = sv.w * mv.w;
            ss[j].x = sv.x * sv.x; ss[j].y = sv.y * sv.y; ss[j].z = sv.z * sv.z; ss[j].w = sv.w * sv.w;
            mm[j].x = mv.x * mv.x; mm[j].y = mv.y * mv.y; mm[j].z = mv.z * mv.z; mm[j].w = mv.w * mv.w;
        }
        float sgn = (invU[gl] < 0.f) ? -1.f : 1.f;
#pragma unroll
        for (int tI = 0; tI < 5; ++tI) {
            int p = ps + tI * 4;
            float na = 0.f, nb = 0.f, nc = 0.f;
#pragma unroll
            for (int j = 0; j < 4; ++j) {
                float4 kv = *(const float4*)&sh.e.k2s[p * D + j * 64 + dg * 4];
                na += sm[j].x * kv.x + sm[j].y * kv.y + sm[j].z * kv.z + sm[j].w * kv.w;
                nb += ss[j].x * kv.x + ss[j].y * kv.y + ss[j].z * kv.z + ss[j].w * kv.w;
                nc += mm[j].x * kv.x + mm[j].y * kv.y + mm[j].z * kv.z + mm[j].w * kv.w;
            }
#pragma unroll
            for (int o = 8; o; o >>= 1) {
                na += __shfl_down(na, o, 16);
                nb += __shfl_down(nb, o, 16);
                nc += __shfl_down(nc, o, 16);
            }
            if (dg == 0) {
                out[(size_t)gl * P + p] = sgn * na * rsqrtf(fmaxf(nb, EPS)) *
                                          rsqrtf(fmaxf(nc, EPS));
            }
        }
    }
}

extern "C" void kernel_launch(void* const* d_in, const int* in_sizes, int n_in,
                              void* d_out, int out_size, void* d_ws, size_t ws_size,
                              hipStream_t stream) {
    const float* s1   = (const float*)d_in[0];
    const float* s2   = (const float*)d_in[1];
    const float* kern = (const float*)d_in[2];
    float* out = (float*)d_out;
    float* ws  = (float*)d_ws;

    float* tp   = ws;
    float* invU = ws + 131072;
    unsigned short* s1f = (unsigned short*)(ws + 147456);
    unsigned short* CT  = (unsigned short*)(ws + 2244608);
    unsigned short* Gf  = (unsigned short*)(ws + 4341760);
    float* Gp   = ws + 4866048;

    k_prep2<<<512, 256, 0, stream>>>(s2, tp, CT);
    k_u<<<4096, 256, 0, stream>>>(s1, tp, invU, s1f);
    k_gram_mfma<<<512, 256, 0, stream>>>(CT, Gp);
    k_reduceG<<<1024, 256, 0, stream>>>(Gp, Gf);
    k_mavout<<<512, 256, 0, stream>>>(s1f, Gf, invU, kern, out);
}